// Round 1
// baseline (133.477 us; speedup 1.0000x reference)
//
#include <hip/hip_runtime.h>

#define N_SAMP 16384
#define D_FEAT 64

typedef __attribute__((ext_vector_type(8))) short bf16x8;
typedef __attribute__((ext_vector_type(4))) float f32x4;
typedef __attribute__((ext_vector_type(4))) unsigned short u16x4;

typedef __attribute__((address_space(3))) unsigned lds_u32_t;
typedef const __attribute__((address_space(1))) unsigned glb_u32_t;

__device__ __forceinline__ void load16_to_lds(const void* g, void* l) {
  __builtin_amdgcn_global_load_lds((glb_u32_t*)g, (lds_u32_t*)l, 16, 0, 0);
}

__device__ __forceinline__ unsigned short f2bf_rne(float f) {
  union { float f; unsigned u; } v;
  v.f = f;
  unsigned u = v.u;
  return (unsigned short)((u + 0x7FFFu + ((u >> 16) & 1u)) >> 16);
}

// Prepass: xb[i][k] = bf16( y_i * x[i][k] )   (y = +-1, so no rounding change)
__global__ __launch_bounds__(256) void prep_kernel(
    const float* __restrict__ x, const float* __restrict__ y,
    unsigned short* __restrict__ xb) {
  int t = blockIdx.x * 256 + threadIdx.x;  // 0 .. 262143
  int base = t * 4;
  int row = base >> 6;  // D=64
  float yv = y[row];
  float4 v = *(const float4*)(x + base);
  u16x4 o;
  o.x = f2bf_rne(v.x * yv);
  o.y = f2bf_rne(v.y * yv);
  o.z = f2bf_rne(v.z * yv);
  o.w = f2bf_rne(v.w * yv);
  *(u16x4*)(xb + base) = o;
}

// Main: each block computes the scalar partial of one 128x128 Gram tile.
// acc init = y_i*y_j*coeff; MFMA adds (y_i x_i)·(y_j x_j) = y_i y_j g
// => T = y_i y_j (g + coeff); odd degree => T^d = y_i y_j (g+coeff)^d,
// contribution = a_j * T^d.
__global__ __launch_bounds__(256, 2) void tile_kernel(
    const unsigned short* __restrict__ xb,
    const float* __restrict__ alpha,
    const float* __restrict__ y,
    const int* __restrict__ coeffp,
    const int* __restrict__ degp,
    float* __restrict__ partials) {
  __shared__ unsigned short smA[128 * 64];
  __shared__ unsigned short smB[128 * 64];
  __shared__ float wred[4];

  const int tid = threadIdx.x;
  const int lane = tid & 63;
  const int wv = tid >> 6;        // wave 0..3
  const int wm = wv >> 1;         // wave row (0..1)
  const int wn = wv & 1;          // wave col (0..1)
  const int lr = lane & 15;
  const int q = lane >> 4;        // quad 0..3

  const int I0 = blockIdx.y * 128;
  const int J0 = blockIdx.x * 128;

  // ---- stage A (rows I0..I0+127) and B (rows J0..J0+127) tiles ----
  // 16B chunk (r, c) of a tile (c = 0..7 within the 128B row) is stored at
  // LDS slot r*8 + (c ^ (r&7))  -> conflict-free ds_read_b128 frag reads.
  const char* xbytes = (const char*)xb;
  char* smAb = (char*)smA;
  char* smBb = (char*)smB;
#pragma unroll
  for (int it = 0; it < 4; ++it) {
    int slotbase = it * 256 + wv * 64;  // wave-uniform
    int S = slotbase + lane;
    int r = S >> 3;
    int c = (S & 7) ^ (r & 7);
    load16_to_lds(xbytes + (((size_t)(I0 + r)) << 7) + (c << 4),
                  smAb + (slotbase << 4));
    load16_to_lds(xbytes + (((size_t)(J0 + r)) << 7) + (c << 4),
                  smBb + (slotbase << 4));
  }

  // ---- scalar params + y/alpha fetches (overlap with staging) ----
  const float fco = (float)coeffp[0];
  const int deg = degp[0];

  float4 yrow[4];
  float ycol[4], wcol[4];
#pragma unroll
  for (int mt = 0; mt < 4; ++mt)
    yrow[mt] = *(const float4*)(y + I0 + wm * 64 + mt * 16 + q * 4);
#pragma unroll
  for (int nt = 0; nt < 4; ++nt) {
    int j = J0 + wn * 64 + nt * 16 + lr;
    ycol[nt] = y[j];
    wcol[nt] = fmaxf(alpha[j], 0.0f);
  }

  // acc[mt][nt] element rg maps to C[row = q*4+rg][col = lr] (m89/m91 layout)
  f32x4 acc[4][4];
#pragma unroll
  for (int mt = 0; mt < 4; ++mt) {
#pragma unroll
    for (int nt = 0; nt < 4; ++nt) {
      float s = ycol[nt] * fco;
      acc[mt][nt][0] = yrow[mt].x * s;
      acc[mt][nt][1] = yrow[mt].y * s;
      acc[mt][nt][2] = yrow[mt].z * s;
      acc[mt][nt][3] = yrow[mt].w * s;
    }
  }

  __syncthreads();  // drains global_load_lds (vmcnt) per m97 semantics

  // ---- LDS -> frags: A[m=lr][k=q*8+j], same pattern for B (NT gemm) ----
  bf16x8 af[4][2], bfr[4][2];
#pragma unroll
  for (int mt = 0; mt < 4; ++mt) {
    int r = wm * 64 + mt * 16 + lr;
#pragma unroll
    for (int kc = 0; kc < 2; ++kc) {
      int c = kc * 4 + q;
      af[mt][kc] = *(const bf16x8*)(smAb + (r << 7) + ((c ^ (r & 7)) << 4));
    }
  }
#pragma unroll
  for (int nt = 0; nt < 4; ++nt) {
    int r = wn * 64 + nt * 16 + lr;
#pragma unroll
    for (int kc = 0; kc < 2; ++kc) {
      int c = kc * 4 + q;
      bfr[nt][kc] = *(const bf16x8*)(smBb + (r << 7) + ((c ^ (r & 7)) << 4));
    }
  }

  // ---- MFMA: K=64 in two chunks, 32 MFMAs/wave ----
#pragma unroll
  for (int kc = 0; kc < 2; ++kc) {
#pragma unroll
    for (int mt = 0; mt < 4; ++mt) {
#pragma unroll
      for (int nt = 0; nt < 4; ++nt) {
        acc[mt][nt] = __builtin_amdgcn_mfma_f32_16x16x32_bf16(
            af[mt][kc], bfr[nt][kc], acc[mt][nt], 0, 0, 0);
      }
    }
  }

  // ---- epilogue: 2 VALU/element (deg==3 fast path) ----
  float lane_sum = 0.0f;
  if (deg == 3) {
#pragma unroll
    for (int nt = 0; nt < 4; ++nt) {
      float colsum = 0.0f;
#pragma unroll
      for (int mt = 0; mt < 4; ++mt) {
#pragma unroll
        for (int rg = 0; rg < 4; ++rg) {
          float T = acc[mt][nt][rg];
          colsum = fmaf(T * T, T, colsum);
        }
      }
      lane_sum = fmaf(colsum, wcol[nt], lane_sum);
    }
  } else {
    // generic degree; for even degree undo the y_i*y_j sign folding
#pragma unroll
    for (int nt = 0; nt < 4; ++nt) {
      float colsum = 0.0f;
#pragma unroll
      for (int mt = 0; mt < 4; ++mt) {
#pragma unroll
        for (int rg = 0; rg < 4; ++rg) {
          float T = acc[mt][nt][rg];
          float p = 1.0f;
          for (int d = 0; d < deg; ++d) p *= T;
          if (!(deg & 1)) p *= ((const float*)&yrow[mt])[rg] * ycol[nt];
          colsum += p;
        }
      }
      lane_sum = fmaf(colsum, wcol[nt], lane_sum);
    }
  }

  // ---- block reduce -> one partial per tile (deterministic) ----
#pragma unroll
  for (int off = 32; off > 0; off >>= 1)
    lane_sum += __shfl_down(lane_sum, off, 64);
  if (lane == 0) wred[wv] = lane_sum;
  __syncthreads();
  if (tid == 0)
    partials[blockIdx.y * gridDim.x + blockIdx.x] =
        wred[0] + wred[1] + wred[2] + wred[3];
}

__global__ __launch_bounds__(1024) void finalize_kernel(
    const float* __restrict__ partials,
    const float* __restrict__ alpha,
    const float* __restrict__ xi,
    const float* __restrict__ y,
    const float* __restrict__ bp,
    const int* __restrict__ Cp,
    const int* __restrict__ lamp,
    float* __restrict__ out) {
  double tsum = 0.0, sa = 0.0, sxi = 0.0, sy = 0.0;
  for (int i = threadIdx.x; i < N_SAMP; i += 1024) {
    tsum += (double)partials[i];
    sa += (double)fmaxf(alpha[i], 0.0f);
    sxi += (double)fmaxf(xi[i], 0.0f);
    sy += (double)y[i];
  }
#pragma unroll
  for (int off = 32; off > 0; off >>= 1) {
    tsum += __shfl_down(tsum, off, 64);
    sa += __shfl_down(sa, off, 64);
    sxi += __shfl_down(sxi, off, 64);
    sy += __shfl_down(sy, off, 64);
  }
  __shared__ double red[16][4];
  int wv = threadIdx.x >> 6;
  if ((threadIdx.x & 63) == 0) {
    red[wv][0] = tsum;
    red[wv][1] = sa;
    red[wv][2] = sxi;
    red[wv][3] = sy;
  }
  __syncthreads();
  if (threadIdx.x == 0) {
    double T = 0, A = 0, X = 0, Y = 0;
    for (int k = 0; k < 16; ++k) {
      T += red[k][0];
      A += red[k][1];
      X += red[k][2];
      Y += red[k][3];
    }
    double b = (double)bp[0];
    double Cc = (double)Cp[0];
    double lam = (double)lamp[0];
    double mean = (T + b * Y - (double)N_SAMP + X) / (double)N_SAMP;
    double loss = 0.5 * A + Cc * X + lam * mean;
    out[0] = (float)loss;
  }
}

extern "C" void kernel_launch(void* const* d_in, const int* in_sizes, int n_in,
                              void* d_out, int out_size, void* d_ws,
                              size_t ws_size, hipStream_t stream) {
  const float* x = (const float*)d_in[0];
  const float* y = (const float*)d_in[1];
  const float* alpha = (const float*)d_in[2];
  const float* xi = (const float*)d_in[3];
  const float* b = (const float*)d_in[4];
  const int* coeff = (const int*)d_in[5];
  const int* degree = (const int*)d_in[6];
  const int* C = (const int*)d_in[7];
  const int* lambd = (const int*)d_in[8];

  unsigned short* xb = (unsigned short*)d_ws;                       // 2 MB
  float* partials = (float*)((char*)d_ws + (size_t)N_SAMP * D_FEAT * 2);  // 64 KB

  prep_kernel<<<(N_SAMP * D_FEAT) / (4 * 256), 256, 0, stream>>>(x, y, xb);

  dim3 grid(N_SAMP / 128, N_SAMP / 128);
  tile_kernel<<<grid, 256, 0, stream>>>(xb, alpha, y, coeff, degree, partials);

  finalize_kernel<<<1, 1024, 0, stream>>>(partials, alpha, xi, y, b, C, lambd,
                                          (float*)d_out);
}